// Round 11
// baseline (132.042 us; speedup 1.0000x reference)
//
#include <hip/hip_runtime.h>
#include <hip/hip_bf16.h>

// Causal attention B=2,H=12,S=2048,D=64 fp32 in/out.
// R22 = R21 inner loop with SPLIT-K DELETED: one dispatch, 384 blocks
// (24 bh x 16 mt2), each walks its full causal kv range (2*mt2+2 tiles,
// max 32). Rationale (R16/R17/R21 post-mortem): totals 126.6/127.7/129.7
// vs fa 42.2/41.3/~40 -- total is harness-overhead dominated; 1-2us fa
// deltas invisible. Split-K cost: reduce dispatch (~6us) + boundary
// (~5-10us) + 19MB partials traffic + 960 prologues + bf16 O round-trip.
// Capacity: 384 blocks < 768 co-resident (3 blocks/CU, 32KB LDS) -> whole
// grid runs in ONE scheduling round; split-K's tail motivation is void.
// Imbalance: worst CU ~38 tile-iters vs 25.5 avg (1.3x), cheaper than the
// overhead removed. R10 evidence (chunk=4 == chunk=8) says wall is not
// chunk latency. O stays f32 end-to-end (accuracy same or better).
// Carried from R21/R20: mfma_f32_32x32x16 QK+PV; S^T C-layout col=q=l&31,
// row=kv=(reg&3)+8*(reg>>2)+4hb; kv-permuted V slots (slot r holds kv
// swapbits23(r)) so PV A-frag = own pk quads directly (zero shfl/select);
// l = lane-local f32 sum + 1 epilogue shfl; V^T [d][kv] 16B-XOR LDS;
// K layout R11; LDS 32KB dbuf; (256,3) cap ~170 regs (84 arch + 64 acc,
// spill-free -- (256,4)=128 cap spills, R19/R20 lesson); bit_cast-only
// packing (rule #20); Q-direct load; XCD swizzle (3 heads/XCD);
// 1 barrier/iter; static-max base-2 softmax; s_setprio on MFMA clusters.
// R13: keep LDS staging (latency hider). R12: no device fences in-kernel.

#define SEQ 2048
#define DH 64
#define NHEADS 24
#define BN 64

typedef float f32x4 __attribute__((ext_vector_type(4)));
typedef float f32x16 __attribute__((ext_vector_type(16)));
typedef __bf16 bf16x8 __attribute__((ext_vector_type(8)));
typedef __bf16 bf16x4 __attribute__((ext_vector_type(4)));
typedef unsigned int u32;
typedef u32 u32x4 __attribute__((ext_vector_type(4)));
typedef unsigned short u16;

#if __has_builtin(__builtin_amdgcn_exp2f)
#define EXP2F(x) __builtin_amdgcn_exp2f(x)
#else
#define EXP2F(x) exp2f(x)
#endif

#define QSCALE 0.1803368801111204f   // log2(e)/8: folds 1/sqrt(64) + base-2

static __device__ __forceinline__ u32 pk2(float a, float b) {
    u16 ua = __builtin_bit_cast(u16, (__bf16)a);
    u16 ub = __builtin_bit_cast(u16, (__bf16)b);
    return (u32)ua | ((u32)ub << 16);
}

// ---------------- main: BM=128, full causal range per block, 32x32 MFMA ----------------
__global__ __launch_bounds__(256, 3)
void fa22_kernel(const float* __restrict__ q, const float* __restrict__ k,
                 const float* __restrict__ v, float* __restrict__ out)
{
    const int bx = blockIdx.x;             // 384 = 8 XCDs x 3 headgrp x 16 mt2
    const int xcd = bx & 7;
    const int sub = bx >> 3;               // 0..47
    const int bh = (sub >> 4) * 8 + xcd;   // 3 heads pinned per XCD
    const int mt2 = 15 - (sub & 15);       // heavy-first within XCD
    const int jt_end = 2 * mt2 + 2;        // full causal kv range, <=32 tiles
    const int q0 = mt2 * 128;

    const int tid = threadIdx.x;
    const int w = tid >> 6, lane = tid & 63;
    const int l31 = lane & 31;
    const int hb = lane >> 5;              // 0/1 half of wave

    __shared__ __bf16 Ks[2][4096];         // 16 KB double-buffered [kv][d] swz
    __shared__ __bf16 Vs[2][4096];         // 16 KB, V^T [d][kv-slot] swz

    const float* kh = k + (size_t)bh * SEQ * DH;
    const float* vh = v + (size_t)bh * SEQ * DH;
    const int qg = q0 + w * 32 + l31;      // this lane's q-row (global)

    // Q fragments, B-operand layout for 32x32x16: col=l31, k=16ks+8hb+j
    bf16x8 qn[4];
    {
        const float* qp = q + (size_t)bh * SEQ * DH + (size_t)qg * DH + hb * 8;
        #pragma unroll
        for (int ks = 0; ks < 4; ++ks) {
            f32x4 x0 = *(const f32x4*)(qp + 16 * ks);
            f32x4 x1 = *(const f32x4*)(qp + 16 * ks + 4);
            #pragma unroll
            for (int j = 0; j < 4; ++j) {
                qn[ks][j]     = (__bf16)(x0[j] * QSCALE);
                qn[ks][4 + j] = (__bf16)(x1[j] * QSCALE);
            }
        }
    }

    f32x16 acc_o0 = {}, acc_o1 = {};       // O [q x d]: dt=0,1
    float lsum = 0.0f;                     // lane-local: q-row l31, own kv residues

    // K staging map (R11-identical): rows srow0, srow0+32
    const int srow0 = tid >> 3;
    const int sg    = tid & 7;
    const int klg   = sg ^ (srow0 & 7);

    // V staging map: thread owns 4 slot-rows x 4d; bank bits in tid[3:0].
    // Slot row r holds GLOBAL kv = swapbits23(r): load from kb2, store at kb.
    const int kb    = (tid & 7) * 4 + ((tid & 128) >> 2);
    const int kb2   = (kb & ~0xC) | ((kb & 4) << 1) | ((kb & 8) >> 1);
    const int dbase = ((tid >> 3) & 15) * 4;

    f32x4 ka[2][2], va[4];
    auto issueKV = [&](int jt) {
        const float* kp = kh + (size_t)(jt * BN + srow0) * DH + klg * 8;
        ka[0][0] = *(const f32x4*)kp;
        ka[0][1] = *(const f32x4*)(kp + 4);
        kp += 32 * DH;
        ka[1][0] = *(const f32x4*)kp;
        ka[1][1] = *(const f32x4*)(kp + 4);
        const float* vpx = vh + (size_t)(jt * BN + kb2) * DH + dbase;
        #pragma unroll
        for (int ii = 0; ii < 4; ++ii) va[ii] = *(const f32x4*)(vpx + ii * DH);
    };
    auto commitKV = [&](int b) {
        #pragma unroll
        for (int s = 0; s < 2; ++s) {
            bf16x8 o;
            #pragma unroll
            for (int jj = 0; jj < 4; ++jj) {
                o[jj]     = (__bf16)ka[s][0][jj];
                o[4 + jj] = (__bf16)ka[s][1][jj];
            }
            *(bf16x8*)((char*)Ks[b] + s * 4096 + tid * 16) = o;
        }
        #pragma unroll
        for (int dd = 0; dd < 4; ++dd) {   // in-register 4x4 transpose, b64 out
            const int d = dbase + dd;
            bf16x4 p4v;
            #pragma unroll
            for (int ii = 0; ii < 4; ++ii) p4v[ii] = (__bf16)va[ii][dd];
            *(bf16x4*)((char*)Vs[b] + d * 128 +
                       ((((kb >> 3) ^ (d & 7)) << 4) | ((kb & 7) * 2))) = p4v;
        }
    };

    // ---- prologue: tile 0 -> buf0; issue loads for tile 1 ----
    issueKV(0);
    commitKV(0);
    if (1 < jt_end) issueKV(1);
    __syncthreads();

    int buf = 0;
    for (int jt = 0; jt < jt_end; ++jt) {
        if (jt + 1 < jt_end) commitKV(buf ^ 1);
        if (jt + 2 < jt_end) issueKV(jt + 2);

        // ---- S^T = K * Q^T (2 kv-tiles x 4 k-steps, 8 MFMA) ----
        const char* Kb = (const char*)Ks[buf];
        const char* Vb = (const char*)Vs[buf];
        f32x16 sa0 = {}, sa1 = {};
        __builtin_amdgcn_s_setprio(1);
        #pragma unroll
        for (int ks = 0; ks < 4; ++ks) {
            bf16x8 kf0 = *(const bf16x8*)(Kb + l31 * 128 +
                                          (((2 * ks + hb) ^ (lane & 7)) << 4));
            bf16x8 kf1 = *(const bf16x8*)(Kb + (32 + l31) * 128 +
                                          (((2 * ks + hb) ^ (lane & 7)) << 4));
            sa0 = __builtin_amdgcn_mfma_f32_32x32x16_bf16(kf0, qn[ks], sa0, 0, 0, 0);
            sa1 = __builtin_amdgcn_mfma_f32_32x32x16_bf16(kf1, qn[ks], sa1, 0, 0, 0);
        }
        __builtin_amdgcn_s_setprio(0);

        if (jt >= 2 * mt2) {               // diagonal region: causal mask
            #pragma unroll
            for (int reg = 0; reg < 16; ++reg) {
                const int kvr = jt * 64 + (reg & 3) + 8 * (reg >> 2) + 4 * hb;
                if (kvr > qg)      sa0[reg] = -1e30f;
                if (kvr + 32 > qg) sa1[reg] = -1e30f;
            }
        }

        // ---- softmax: in-place exp2, lane-local l sum, pack to u32 quads ----
        u32 pk[8][2];                      // all static-indexed (rule #20)
        #pragma unroll
        for (int sp = 0; sp < 4; ++sp) {
            float e0 = EXP2F(sa0[4 * sp + 0]), e1 = EXP2F(sa0[4 * sp + 1]);
            float e2 = EXP2F(sa0[4 * sp + 2]), e3 = EXP2F(sa0[4 * sp + 3]);
            float f0 = EXP2F(sa1[4 * sp + 0]), f1 = EXP2F(sa1[4 * sp + 1]);
            float f2 = EXP2F(sa1[4 * sp + 2]), f3 = EXP2F(sa1[4 * sp + 3]);
            lsum += ((e0 + e1) + (e2 + e3)) + ((f0 + f1) + (f2 + f3));
            pk[sp][0]     = pk2(e0, e1); pk[sp][1]     = pk2(e2, e3);
            pk[4 + sp][0] = pk2(f0, f1); pk[4 + sp][1] = pk2(f2, f3);
        }

        // ---- O += P V. A-frag = own quads directly (kv-permuted V slots) ----
        __builtin_amdgcn_s_setprio(1);
        #pragma unroll
        for (int s = 0; s < 4; ++s) {
            u32x4 uv;
            uv[0] = pk[2 * s][0];
            uv[1] = pk[2 * s][1];
            uv[2] = pk[2 * s + 1][0];
            uv[3] = pk[2 * s + 1][1];
            bf16x8 pf = __builtin_bit_cast(bf16x8, uv);
            bf16x8 vf0 = *(const bf16x8*)(Vb + l31 * 128 +
                                          (((2 * s + hb) ^ (lane & 7)) << 4));
            bf16x8 vf1 = *(const bf16x8*)(Vb + (32 + l31) * 128 +
                                          (((2 * s + hb) ^ (lane & 7)) << 4));
            acc_o0 = __builtin_amdgcn_mfma_f32_32x32x16_bf16(pf, vf0, acc_o0, 0, 0, 0);
            acc_o1 = __builtin_amdgcn_mfma_f32_32x32x16_bf16(pf, vf1, acc_o1, 0, 0, 0);
        }
        __builtin_amdgcn_s_setprio(0);

        if (jt + 1 < jt_end) __syncthreads();
        buf ^= 1;
    }

    // full l for q-row l31: both kv-parity halves
    const float ltot = lsum + __shfl_xor(lsum, 32, 64);

    // ---- epilogue: broadcast l per C-row, normalize, f32 direct out ----
    float* oh = out + (size_t)bh * SEQ * DH;
    #pragma unroll
    for (int reg = 0; reg < 16; ++reg) {
        const int rr = (reg & 3) + 8 * (reg >> 2) + 4 * hb;
        const float lr = __shfl(ltot, rr, 64);   // lane rr holds l(q=w*32+rr)
        const float inv = 1.0f / lr;
        const int row = q0 + w * 32 + rr;
        oh[(size_t)row * DH + l31]      = acc_o0[reg] * inv;
        oh[(size_t)row * DH + 32 + l31] = acc_o1[reg] * inv;
    }
}

extern "C" void kernel_launch(void* const* d_in, const int* in_sizes, int n_in,
                              void* d_out, int out_size, void* d_ws, size_t ws_size,
                              hipStream_t stream) {
    (void)in_sizes; (void)n_in; (void)out_size; (void)d_ws; (void)ws_size;
    const float* q = (const float*)d_in[0];
    const float* k = (const float*)d_in[1];
    const float* v = (const float*)d_in[2];
    float* out = (float*)d_out;

    fa22_kernel<<<dim3(384), dim3(256), 0, stream>>>(q, k, v, out);
}

// Round 12
// 130.660 us; speedup vs baseline: 1.0106x; 1.0106x over previous
//
#include <hip/hip_runtime.h>
#include <hip/hip_bf16.h>

// Causal attention B=2,H=12,S=2048,D=64 fp32 in/out.
// R23 = R21 verbatim (lock-in). Rationale: R22's balanced-less single
// dispatch regressed (fa 56us, occupancy 8% -- work quantum 32 iters >
// per-CU average 25.5 -> drain tail; the 14us dispatch saving < 16us
// imbalance). Totals across R16/R17/R21 (126.6/127.7/129.7) are noise-
// dominated (~42us fill + ~35us fixed overhead); by the lower-noise
// GPU-kernel-time metric R21 is best (fa ~40 + reduce 6). A balanced
// single-dispatch redesign (BN=32/BM=64/768 blocks) needs fresh bank maps
// on 3 paths -- negative risk-adjusted EV this late. Locking R21.
// R21 = R20 + kv-permuted V slots: MFMA sums over k-slots, so slot->kv
// bijection is free; choose the kv each lane half ALREADY holds from the
// S^T C-layout -> PV A-frag = own pk quads directly (zero shfl/select).
// V slot row r holds kv swapbits23(r): load global row kb2 for slot kb.
// R20 lesson: unified VGPR file -- (256,4) cap 128 spills this structure;
// (256,3) cap ~170 fits (84 arch + acc, WRITE 17MB clean). R19: bit_cast
// only, no address-of-local vectors (rule #20). R18: 32x32x16 both GEMMs,
// S^T C col=q=l&31, row=kv=(reg&3)+8*(reg>>2)+4hb; l = lane-local f32 sum
// + 1 epilogue shfl. V^T [d][kv] 16B-XOR LDS; K layout R11; LDS 32KB dbuf.
// Carried: fused prep (2 dispatches), split-K chunks of 8 k-tiles (960
// blocks, balance re-validated by R22's counterexample), Q-direct load,
// single-chunk q-tiles direct-out, XCD swizzle (3 heads/XCD), 1 barrier/
// iter, bf16 partial O + f32 l, static-max base-2 softmax, s_setprio on
// MFMA clusters. R13: keep LDS staging. R12: no device fences in-kernel.

#define SEQ 2048
#define DH 64
#define NHEADS 24
#define BN 64
#define LDK 72
#define NSLOT (NHEADS * 16 * 4)                       // 1536
#define WS_FA14  ((size_t)NSLOT * 8192 * 2 + (size_t)NSLOT * 128 * 4)

typedef float f32x4 __attribute__((ext_vector_type(4)));
typedef float f32x16 __attribute__((ext_vector_type(16)));
typedef __bf16 bf16x8 __attribute__((ext_vector_type(8)));
typedef __bf16 bf16x4 __attribute__((ext_vector_type(4)));
typedef unsigned int u32;
typedef u32 u32x4 __attribute__((ext_vector_type(4)));
typedef unsigned short u16;

#if __has_builtin(__builtin_amdgcn_exp2f)
#define EXP2F(x) __builtin_amdgcn_exp2f(x)
#else
#define EXP2F(x) exp2f(x)
#endif

#define QSCALE 0.1803368801111204f   // log2(e)/8: folds 1/sqrt(64) + base-2

static __device__ __forceinline__ u32 pk2(float a, float b) {
    u16 ua = __builtin_bit_cast(u16, (__bf16)a);
    u16 ub = __builtin_bit_cast(u16, (__bf16)b);
    return (u32)ua | ((u32)ub << 16);
}

// ---------------- main: BM=128, split-K(8), dbuf, 32x32 MFMA, reg-P ----------------
__global__ __launch_bounds__(256, 3)
void fa23_kernel(const float* __restrict__ q, const float* __restrict__ k,
                 const float* __restrict__ v,
                 __bf16* __restrict__ opart, float* __restrict__ lpart,
                 float* __restrict__ out)
{
    const int bx = blockIdx.x;             // 960 = 8 XCDs x 3 headgrp x 40
    const int xcd = bx & 7;
    const int sub = bx >> 3;               // 0..119
    const int bh = (sub / 40) * 8 + xcd;   // 3 heads pinned per XCD
    const int rem = 39 - (sub % 40);       // heavy-first within XCD
    int mt2, st;
    if      (rem >= 36) { mt2 = 15; st = 36; }
    else if (rem >= 32) { mt2 = 14; st = 32; }
    else if (rem >= 28) { mt2 = 13; st = 28; }
    else if (rem >= 24) { mt2 = 12; st = 24; }
    else if (rem >= 21) { mt2 = 11; st = 21; }
    else if (rem >= 18) { mt2 = 10; st = 18; }
    else if (rem >= 15) { mt2 = 9;  st = 15; }
    else if (rem >= 12) { mt2 = 8;  st = 12; }
    else if (rem >= 10) { mt2 = 7;  st = 10; }
    else if (rem >= 8)  { mt2 = 6;  st = 8; }
    else if (rem >= 6)  { mt2 = 5;  st = 6; }
    else if (rem >= 4)  { mt2 = 4;  st = 4; }
    else                { mt2 = rem; st = rem; }
    const int chunk = rem - st;
    const int jt0 = chunk * 8;
    const int jt_end = min(jt0 + 8, 2 * mt2 + 2);
    const int q0 = mt2 * 128;

    const int tid = threadIdx.x;
    const int w = tid >> 6, lane = tid & 63;
    const int l31 = lane & 31;
    const int hb = lane >> 5;              // 0/1 half of wave

    __shared__ __bf16 Ks[2][4096];         // 16 KB double-buffered [kv][d] swz
    __shared__ __bf16 Vs[2][4096];         // 16 KB, V^T [d][kv-slot] swz

    const float* kh = k + (size_t)bh * SEQ * DH;
    const float* vh = v + (size_t)bh * SEQ * DH;
    const int qg = q0 + w * 32 + l31;      // this lane's q-row (global)

    // Q fragments, B-operand layout for 32x32x16: col=l31, k=16ks+8hb+j
    bf16x8 qn[4];
    {
        const float* qp = q + (size_t)bh * SEQ * DH + (size_t)qg * DH + hb * 8;
        #pragma unroll
        for (int ks = 0; ks < 4; ++ks) {
            f32x4 x0 = *(const f32x4*)(qp + 16 * ks);
            f32x4 x1 = *(const f32x4*)(qp + 16 * ks + 4);
            #pragma unroll
            for (int j = 0; j < 4; ++j) {
                qn[ks][j]     = (__bf16)(x0[j] * QSCALE);
                qn[ks][4 + j] = (__bf16)(x1[j] * QSCALE);
            }
        }
    }

    f32x16 acc_o0 = {}, acc_o1 = {};       // O [q x d]: dt=0,1
    float lsum = 0.0f;                     // lane-local: q-row l31, own kv residues

    // K staging map (R11-identical): rows srow0, srow0+32
    const int srow0 = tid >> 3;
    const int sg    = tid & 7;
    const int klg   = sg ^ (srow0 & 7);

    // V staging map: thread owns 4 slot-rows x 4d; bank bits in tid[3:0].
    // Slot row r holds GLOBAL kv = swapbits23(r): load from kb2, store at kb.
    const int kb    = (tid & 7) * 4 + ((tid & 128) >> 2);
    const int kb2   = (kb & ~0xC) | ((kb & 4) << 1) | ((kb & 8) >> 1);
    const int dbase = ((tid >> 3) & 15) * 4;

    f32x4 ka[2][2], va[4];
    auto issueKV = [&](int jt) {
        const float* kp = kh + (size_t)(jt * BN + srow0) * DH + klg * 8;
        ka[0][0] = *(const f32x4*)kp;
        ka[0][1] = *(const f32x4*)(kp + 4);
        kp += 32 * DH;
        ka[1][0] = *(const f32x4*)kp;
        ka[1][1] = *(const f32x4*)(kp + 4);
        const float* vpx = vh + (size_t)(jt * BN + kb2) * DH + dbase;
        #pragma unroll
        for (int ii = 0; ii < 4; ++ii) va[ii] = *(const f32x4*)(vpx + ii * DH);
    };
    auto commitKV = [&](int b) {
        #pragma unroll
        for (int s = 0; s < 2; ++s) {
            bf16x8 o;
            #pragma unroll
            for (int jj = 0; jj < 4; ++jj) {
                o[jj]     = (__bf16)ka[s][0][jj];
                o[4 + jj] = (__bf16)ka[s][1][jj];
            }
            *(bf16x8*)((char*)Ks[b] + s * 4096 + tid * 16) = o;
        }
        #pragma unroll
        for (int dd = 0; dd < 4; ++dd) {   // in-register 4x4 transpose, b64 out
            const int d = dbase + dd;
            bf16x4 p4v;
            #pragma unroll
            for (int ii = 0; ii < 4; ++ii) p4v[ii] = (__bf16)va[ii][dd];
            *(bf16x4*)((char*)Vs[b] + d * 128 +
                       ((((kb >> 3) ^ (d & 7)) << 4) | ((kb & 7) * 2))) = p4v;
        }
    };

    // ---- prologue: tile jt0 -> buf0; issue loads for jt0+1 ----
    issueKV(jt0);
    commitKV(0);
    if (jt0 + 1 < jt_end) issueKV(jt0 + 1);
    __syncthreads();

    int buf = 0;
    for (int jt = jt0; jt < jt_end; ++jt) {
        if (jt + 1 < jt_end) commitKV(buf ^ 1);
        if (jt + 2 < jt_end) issueKV(jt + 2);

        // ---- S^T = K * Q^T (2 kv-tiles x 4 k-steps, 8 MFMA) ----
        const char* Kb = (const char*)Ks[buf];
        const char* Vb = (const char*)Vs[buf];
        f32x16 sa0 = {}, sa1 = {};
        __builtin_amdgcn_s_setprio(1);
        #pragma unroll
        for (int ks = 0; ks < 4; ++ks) {
            bf16x8 kf0 = *(const bf16x8*)(Kb + l31 * 128 +
                                          (((2 * ks + hb) ^ (lane & 7)) << 4));
            bf16x8 kf1 = *(const bf16x8*)(Kb + (32 + l31) * 128 +
                                          (((2 * ks + hb) ^ (lane & 7)) << 4));
            sa0 = __builtin_amdgcn_mfma_f32_32x32x16_bf16(kf0, qn[ks], sa0, 0, 0, 0);
            sa1 = __builtin_amdgcn_mfma_f32_32x32x16_bf16(kf1, qn[ks], sa1, 0, 0, 0);
        }
        __builtin_amdgcn_s_setprio(0);

        if (jt >= 2 * mt2) {               // diagonal region: causal mask
            #pragma unroll
            for (int reg = 0; reg < 16; ++reg) {
                const int kvr = jt * 64 + (reg & 3) + 8 * (reg >> 2) + 4 * hb;
                if (kvr > qg)      sa0[reg] = -1e30f;
                if (kvr + 32 > qg) sa1[reg] = -1e30f;
            }
        }

        // ---- softmax: in-place exp2, lane-local l sum, pack to u32 quads ----
        u32 pk[8][2];                      // all static-indexed (rule #20)
        #pragma unroll
        for (int sp = 0; sp < 4; ++sp) {
            float e0 = EXP2F(sa0[4 * sp + 0]), e1 = EXP2F(sa0[4 * sp + 1]);
            float e2 = EXP2F(sa0[4 * sp + 2]), e3 = EXP2F(sa0[4 * sp + 3]);
            float f0 = EXP2F(sa1[4 * sp + 0]), f1 = EXP2F(sa1[4 * sp + 1]);
            float f2 = EXP2F(sa1[4 * sp + 2]), f3 = EXP2F(sa1[4 * sp + 3]);
            lsum += ((e0 + e1) + (e2 + e3)) + ((f0 + f1) + (f2 + f3));
            pk[sp][0]     = pk2(e0, e1); pk[sp][1]     = pk2(e2, e3);
            pk[4 + sp][0] = pk2(f0, f1); pk[4 + sp][1] = pk2(f2, f3);
        }

        // ---- O += P V. A-frag = own quads directly (kv-permuted V slots) ----
        __builtin_amdgcn_s_setprio(1);
        #pragma unroll
        for (int s = 0; s < 4; ++s) {
            u32x4 uv;
            uv[0] = pk[2 * s][0];
            uv[1] = pk[2 * s][1];
            uv[2] = pk[2 * s + 1][0];
            uv[3] = pk[2 * s + 1][1];
            bf16x8 pf = __builtin_bit_cast(bf16x8, uv);
            bf16x8 vf0 = *(const bf16x8*)(Vb + l31 * 128 +
                                          (((2 * s + hb) ^ (lane & 7)) << 4));
            bf16x8 vf1 = *(const bf16x8*)(Vb + (32 + l31) * 128 +
                                          (((2 * s + hb) ^ (lane & 7)) << 4));
            acc_o0 = __builtin_amdgcn_mfma_f32_32x32x16_bf16(pf, vf0, acc_o0, 0, 0, 0);
            acc_o1 = __builtin_amdgcn_mfma_f32_32x32x16_bf16(pf, vf1, acc_o1, 0, 0, 0);
        }
        __builtin_amdgcn_s_setprio(0);

        if (jt + 1 < jt_end) __syncthreads();
        buf ^= 1;
    }

    // full l for q-row l31: both kv-parity halves
    const float ltot = lsum + __shfl_xor(lsum, 32, 64);

    if (2 * mt2 + 2 <= 8) {
        // ---- single-chunk q-tile: broadcast l per C-row, write out direct
        float* oh = out + (size_t)bh * SEQ * DH;
        #pragma unroll
        for (int reg = 0; reg < 16; ++reg) {
            const int rr = (reg & 3) + 8 * (reg >> 2) + 4 * hb;
            const float lr = __shfl(ltot, rr, 64);   // lane rr holds l(q=w*32+rr)
            const float inv = 1.0f / lr;
            const int row = q0 + w * 32 + rr;
            oh[(size_t)row * DH + l31]      = acc_o0[reg] * inv;
            oh[(size_t)row * DH + 32 + l31] = acc_o1[reg] * inv;
        }
    } else {
        // ---- partials out (O in bf16; l in f32, lane-owned row) ----
        const int slot = (bh * 16 + mt2) * 4 + chunk;
        __bf16* po = opart + (size_t)slot * 8192;
        #pragma unroll
        for (int reg = 0; reg < 16; ++reg) {
            const int row = w * 32 + (reg & 3) + 8 * (reg >> 2) + 4 * hb;
            po[row * 64 + l31]      = (__bf16)acc_o0[reg];
            po[row * 64 + 32 + l31] = (__bf16)acc_o1[reg];
        }
        if (hb == 0) lpart[(size_t)slot * 128 + w * 32 + l31] = ltot;
    }
}

// ---------------- reduce: sum bf16 chunks, normalize (mt2 >= 4 only) ----------------
__global__ __launch_bounds__(256)
void fa_reduce(const __bf16* __restrict__ opart, const float* __restrict__ lpart,
               float* __restrict__ out)
{
    const int bx = blockIdx.x;             // 288 = 8 XCDs x 3 headgrp x 12
    const int xcd = bx & 7;
    const int r2 = bx >> 3;                // 0..35
    const int bh = (r2 / 12) * 8 + xcd;    // co-locate with producer XCD
    const int mt2 = 4 + (r2 % 12);
    const int nc = (mt2 >> 2) + 1;         // ceil((2*mt2+2)/8)
    const int base = (bh * 16 + mt2) * 4;
    const int tid = threadIdx.x;
    #pragma unroll
    for (int rnd = 0; rnd < 8; ++rnd) {
        const int flat = rnd * 1024 + tid * 4;
        const int row = flat >> 6;
        float o0 = 0, o1 = 0, o2 = 0, o3 = 0, l = 0;
        for (int c = 0; c < nc; ++c) {
            bf16x4 ov = *(const bf16x4*)(opart + (size_t)(base + c) * 8192 + flat);
            o0 += (float)ov[0]; o1 += (float)ov[1]; o2 += (float)ov[2]; o3 += (float)ov[3];
            l += lpart[(size_t)(base + c) * 128 + row];
        }
        const float inv = 1.0f / l;
        f32x4 res = { o0 * inv, o1 * inv, o2 * inv, o3 * inv };
        *(f32x4*)(out + (size_t)bh * SEQ * DH + (size_t)mt2 * 8192 + flat) = res;
    }
}

// ---------------- fallback: R1 self-contained kernel ----------------
__global__ __launch_bounds__(256, 2)
void fa_causal_kernel(const float* __restrict__ q, const float* __restrict__ k,
                      const float* __restrict__ v, float* __restrict__ out)
{
    const int mt = 31 - (blockIdx.x & 31);
    const int bh = blockIdx.x >> 5;
    const int tid = threadIdx.x;
    const int w = tid >> 6, lane = tid & 63;
    const int g = lane >> 4, li = lane & 15;
    const int m0 = mt * 64;
    __shared__ __bf16 KsF[BN][LDK];
    __shared__ __bf16 VsF[DH][LDK];
    __shared__ __bf16 PsF[4][16][LDK];
    const size_t head_off = (size_t)bh * SEQ * DH;
    const float* qh = q + head_off;
    const float* kh = k + head_off;
    const float* vh = v + head_off;
    float* oh = out + head_off;
    const int qrow = m0 + w * 16 + li;
    bf16x8 qf[2];
    {
        const float* qp = qh + (size_t)qrow * DH + g * 8;
        #pragma unroll
        for (int c = 0; c < 2; ++c) {
            const float* p = qp + c * 32;
            #pragma unroll
            for (int jj = 0; jj < 8; ++jj) qf[c][jj] = (__bf16)p[jj];
        }
    }
    f32x4 acc[4] = {};
    float mrow[4], lrow[4];
    #pragma unroll
    for (int r = 0; r < 4; ++r) { mrow[r] = -1e30f; lrow[r] = 0.0f; }
    const float scale = 0.125f;
    const int srow = tid >> 2, scol = (tid & 3) * 16;
    for (int jt = 0; jt <= mt; ++jt) {
        const int kv0 = jt * BN;
        __syncthreads();
        {
            const float* kp = kh + (size_t)(kv0 + srow) * DH + scol;
            __bf16 tmp[16];
            #pragma unroll
            for (int jj = 0; jj < 16; ++jj) tmp[jj] = (__bf16)kp[jj];
            *(bf16x8*)&KsF[srow][scol]     = *(bf16x8*)&tmp[0];
            *(bf16x8*)&KsF[srow][scol + 8] = *(bf16x8*)&tmp[8];
            const float* vp = vh + (size_t)(kv0 + srow) * DH + scol;
            #pragma unroll
            for (int jj = 0; jj < 16; ++jj) VsF[scol + jj][srow] = (__bf16)vp[jj];
        }
        __syncthreads();
        float s4[4][4];
        #pragma unroll
        for (int t = 0; t < 4; ++t) {
            f32x4 sa = {};
            #pragma unroll
            for (int c = 0; c < 2; ++c) {
                bf16x8 kfr = *(const bf16x8*)&KsF[t * 16 + li][c * 32 + g * 8];
                sa = __builtin_amdgcn_mfma_f32_16x16x32_bf16(qf[c], kfr, sa, 0, 0, 0);
            }
            #pragma unroll
            for (int r = 0; r < 4; ++r) s4[t][r] = sa[r] * scale;
        }
        if (jt == mt) {
            #pragma unroll
            for (int t = 0; t < 4; ++t) {
                const int col = kv0 + t * 16 + li;
                #pragma unroll
                for (int r = 0; r < 4; ++r)
                    if (col > m0 + w * 16 + g * 4 + r) s4[t][r] = -1e30f;
            }
        }
        #pragma unroll
        for (int r = 0; r < 4; ++r) {
            float mx = fmaxf(fmaxf(s4[0][r], s4[1][r]), fmaxf(s4[2][r], s4[3][r]));
            #pragma unroll
            for (int off = 1; off < 16; off <<= 1)
                mx = fmaxf(mx, __shfl_xor(mx, off, 64));
            const float mnew = fmaxf(mrow[r], mx);
            const float alpha = __expf(mrow[r] - mnew);
            mrow[r] = mnew;
            float ps = 0.0f;
            #pragma unroll
            for (int t = 0; t < 4; ++t) {
                const float p = __expf(s4[t][r] - mnew);
                s4[t][r] = p;
                ps += p;
            }
            #pragma unroll
            for (int off = 1; off < 16; off <<= 1)
                ps += __shfl_xor(ps, off, 64);
            lrow[r] = lrow[r] * alpha + ps;
            #pragma unroll
            for (int t = 0; t < 4; ++t) acc[t][r] *= alpha;
        }
        #pragma unroll
        for (int t = 0; t < 4; ++t)
            #pragma unroll
            for (int r = 0; r < 4; ++r)
                PsF[w][g * 4 + r][t * 16 + li] = (__bf16)s4[t][r];
        __syncthreads();
        #pragma unroll
        for (int c = 0; c < 2; ++c) {
            bf16x8 pf = *(const bf16x8*)&PsF[w][li][c * 32 + g * 8];
            #pragma unroll
            for (int t = 0; t < 4; ++t) {
                bf16x8 vfr = *(const bf16x8*)&VsF[t * 16 + li][c * 32 + g * 8];
                acc[t] = __builtin_amdgcn_mfma_f32_16x16x32_bf16(pf, vfr, acc[t], 0, 0, 0);
            }
        }
    }
    #pragma unroll
    for (int r = 0; r < 4; ++r) {
        const int row = m0 + w * 16 + g * 4 + r;
        const float inv = 1.0f / lrow[r];
        float* op = oh + (size_t)row * DH + li;
        #pragma unroll
        for (int t = 0; t < 4; ++t) op[t * 16] = acc[t][r] * inv;
    }
}

extern "C" void kernel_launch(void* const* d_in, const int* in_sizes, int n_in,
                              void* d_out, int out_size, void* d_ws, size_t ws_size,
                              hipStream_t stream) {
    (void)in_sizes; (void)n_in; (void)out_size;
    const float* q = (const float*)d_in[0];
    const float* k = (const float*)d_in[1];
    const float* v = (const float*)d_in[2];
    float* out = (float*)d_out;

    if (ws_size >= WS_FA14) {
        __bf16* opart = (__bf16*)d_ws;
        float* lpart = (float*)((char*)d_ws + (size_t)NSLOT * 8192 * 2);
        fa23_kernel<<<dim3(960), dim3(256), 0, stream>>>(q, k, v, opart, lpart, out);
        fa_reduce<<<dim3(288), dim3(256), 0, stream>>>(opart, lpart, out);
    } else {
        fa_causal_kernel<<<dim3(NHEADS * 32), dim3(256), 0, stream>>>(q, k, v, out);
    }
}

// Round 13
// 128.208 us; speedup vs baseline: 1.0299x; 1.0191x over previous
//
#include <hip/hip_runtime.h>
#include <hip/hip_bf16.h>

// Causal attention B=2,H=12,S=2048,D=64 fp32 in/out.
// R24 = R23 inner loop with staging moved to global_load_lds DMA + prep:
//  - R23's reg staging held ka/va (32 arch VGPRs) across each compute phase,
//    pinning the structure at (256,3) = 3 blocks/CU (R19/R20: (256,4) cap
//    128 total in the unified file spills; acc side alone = sa32+acc_o32=64).
//    global_load_lds stages K/V with ZERO register round-trip and zero cvt
//    in the hot loop -> arch ~52 + acc 64 ~= 116 <= 128 -> (256,4), 4
//    blocks/CU (+33% waves for this latency-bound loop), 960 blocks = one
//    scheduling round at 4/CU.
//  - Needs bf16 K/V in global -> R11's proven prep returns (~8us), with
//    R21's kv-permutation (swap bits 2<->3; acts within 16-aligned groups,
//    commutes with prep's 16-elem writes) baked into prep's V gather, so
//    fa's V fill is contiguous 16B slots from a PRE-SWIZZLED source (m173)
//    and the PV read side stays byte-identical to R23.
//  - Fill maps re-derived vs unchanged read maps: K slot byte s*4096+tid*16
//    <-> row s*32+(tid>>3), colgrp (tid&7)^((tid>>3)&7) = sg^(row&7) OK;
//    V slot byte tid*16 (+4096) <-> d=tid>>3 (+32), kvgrp (tid&7)^(d&7) OK.
//    All LDS dests wave-uniform base + lane*16 (gl_lds constraint, m104).
// Carried from R23/R21: mfma_f32_32x32x16 QK+PV; S^T C col=q=l&31,
// row=kv=(reg&3)+8*(reg>>2)+4hb; kv-permuted V slots -> PV A-frag = own pk
// quads (zero shfl/select); l = lane-local f32 sum + 1 epilogue shfl;
// V^T [d][kv] 16B-XOR LDS; K layout R11; LDS 32KB dbuf; bit_cast-only
// packing (rule #20); split-K chunks of 8 k-tiles (960 blocks; balance
// re-validated by R22's counterexample); Q-direct; single-chunk q-tiles
// direct-out; XCD swizzle (3 heads/XCD); 1 barrier/iter; bf16 partial O +
// f32 l; static-max base-2 softmax; s_setprio on MFMA clusters.
// R13: LDS staging = the latency hider. R12: no device fences in-kernel.

#define SEQ 2048
#define DH 64
#define NHEADS 24
#define BN 64
#define LDK 72
#define ELEMS_PER_TENSOR (NHEADS * SEQ * DH)          // 3145728
#define NSLOT (NHEADS * 16 * 4)                       // 1536
#define WS_KV    ((size_t)2 * ELEMS_PER_TENSOR * 2)   // 12582912 B
#define WS_FA11  (WS_KV + (size_t)NSLOT * 8192 * 2 + (size_t)NSLOT * 128 * 4)

typedef float f32x4 __attribute__((ext_vector_type(4)));
typedef float f32x16 __attribute__((ext_vector_type(16)));
typedef __bf16 bf16x8 __attribute__((ext_vector_type(8)));
typedef __bf16 bf16x4 __attribute__((ext_vector_type(4)));
typedef unsigned int u32;
typedef u32 u32x4 __attribute__((ext_vector_type(4)));
typedef unsigned short u16;

#if __has_builtin(__builtin_amdgcn_exp2f)
#define EXP2F(x) __builtin_amdgcn_exp2f(x)
#else
#define EXP2F(x) exp2f(x)
#endif

#define QSCALE 0.1803368801111204f   // log2(e)/8: folds 1/sqrt(64) + base-2

#define GLOAD_LDS16(g, l)                                                     \
    __builtin_amdgcn_global_load_lds(                                         \
        (const __attribute__((address_space(1))) void*)(g),                   \
        (__attribute__((address_space(3))) void*)(l), 16, 0, 0)

static __device__ __forceinline__ u32 pk2(float a, float b) {
    u16 ua = __builtin_bit_cast(u16, (__bf16)a);
    u16 ub = __builtin_bit_cast(u16, (__bf16)b);
    return (u32)ua | ((u32)ub << 16);
}

// ---------------- pre-pass: K -> bf16, V -> bf16 transposed + kv-permuted ----------------
__global__ __launch_bounds__(256)
void prep_kernel(const float* __restrict__ k, const float* __restrict__ v,
                 __bf16* __restrict__ ks, __bf16* __restrict__ vt)
{
    __shared__ __bf16 T[64][LDK];
    const int bx = blockIdx.x;
    const int tid = threadIdx.x;
    if (bx < 1536) {                       // K bf16 convert
        const int idx = (bx * 256 + tid) * 8;
        f32x4 a = *(const f32x4*)(k + idx);
        f32x4 b = *(const f32x4*)(k + idx + 4);
        bf16x8 o;
        #pragma unroll
        for (int j = 0; j < 4; ++j) { o[j] = (__bf16)a[j]; o[4 + j] = (__bf16)b[j]; }
        *(bf16x8*)(ks + idx) = o;
    } else {                               // V transpose to [bh][d][s'], s' kv-permuted
        const int b2 = bx - 1536;
        const int bh = b2 >> 5;
        const int s0 = (b2 & 31) * 64;
        const int r = tid >> 2, c0 = (tid & 3) * 16;
        const float* vp = v + (size_t)bh * SEQ * DH + (size_t)(s0 + r) * DH + c0;
        __bf16 tmp[16];
        #pragma unroll
        for (int jj = 0; jj < 16; ++jj) tmp[jj] = (__bf16)vp[jj];
        *(bf16x8*)&T[r][c0]     = *(bf16x8*)&tmp[0];
        *(bf16x8*)&T[r][c0 + 8] = *(bf16x8*)&tmp[8];
        __syncthreads();
        const int d = tid >> 2, j0 = (tid & 3) * 16;
        __bf16 o[16];
        #pragma unroll
        for (int jj = 0; jj < 16; ++jj) {
            // slot index j0+jj holds global kv s0 + j0 + swap23(jj)
            const int js = (jj & 3) | ((jj & 4) << 1) | ((jj & 8) >> 1);
            o[jj] = T[j0 + js][d];
        }
        __bf16* op = vt + (size_t)bh * DH * SEQ + (size_t)d * SEQ + s0 + j0;
        *(bf16x8*)op       = *(bf16x8*)&o[0];
        *(bf16x8*)(op + 8) = *(bf16x8*)&o[8];
    }
}

// ---------------- main: BM=128, split-K(8), gl_lds dbuf, 32x32 MFMA, reg-P ----------------
__global__ __launch_bounds__(256, 4)
void fa24_kernel(const float* __restrict__ q, const __bf16* __restrict__ ks,
                 const __bf16* __restrict__ vt,
                 __bf16* __restrict__ opart, float* __restrict__ lpart,
                 float* __restrict__ out)
{
    const int bx = blockIdx.x;             // 960 = 8 XCDs x 3 headgrp x 40
    const int xcd = bx & 7;
    const int sub = bx >> 3;               // 0..119
    const int bh = (sub / 40) * 8 + xcd;   // 3 heads pinned per XCD
    const int rem = 39 - (sub % 40);       // heavy-first within XCD
    int mt2, st;
    if      (rem >= 36) { mt2 = 15; st = 36; }
    else if (rem >= 32) { mt2 = 14; st = 32; }
    else if (rem >= 28) { mt2 = 13; st = 28; }
    else if (rem >= 24) { mt2 = 12; st = 24; }
    else if (rem >= 21) { mt2 = 11; st = 21; }
    else if (rem >= 18) { mt2 = 10; st = 18; }
    else if (rem >= 15) { mt2 = 9;  st = 15; }
    else if (rem >= 12) { mt2 = 8;  st = 12; }
    else if (rem >= 10) { mt2 = 7;  st = 10; }
    else if (rem >= 8)  { mt2 = 6;  st = 8; }
    else if (rem >= 6)  { mt2 = 5;  st = 6; }
    else if (rem >= 4)  { mt2 = 4;  st = 4; }
    else                { mt2 = rem; st = rem; }
    const int chunk = rem - st;
    const int jt0 = chunk * 8;
    const int jt_end = min(jt0 + 8, 2 * mt2 + 2);
    const int q0 = mt2 * 128;

    const int tid = threadIdx.x;
    const int w = tid >> 6, lane = tid & 63;
    const int l31 = lane & 31;
    const int hb = lane >> 5;              // 0/1 half of wave

    __shared__ __bf16 Ks[2][4096];         // 16 KB double-buffered [kv][d] swz
    __shared__ __bf16 Vs[2][4096];         // 16 KB, V^T [d][kv-slot] swz

    const __bf16* khb = ks + (size_t)bh * SEQ * DH;
    const __bf16* vhb = vt + (size_t)bh * DH * SEQ;  // [d][s'], kv-permuted
    const int qg = q0 + w * 32 + l31;      // this lane's q-row (global)

    // Q fragments, B-operand layout for 32x32x16: col=l31, k=16ks+8hb+j
    bf16x8 qn[4];
    {
        const float* qp = q + (size_t)bh * SEQ * DH + (size_t)qg * DH + hb * 8;
        #pragma unroll
        for (int kq = 0; kq < 4; ++kq) {
            f32x4 x0 = *(const f32x4*)(qp + 16 * kq);
            f32x4 x1 = *(const f32x4*)(qp + 16 * kq + 4);
            #pragma unroll
            for (int j = 0; j < 4; ++j) {
                qn[kq][j]     = (__bf16)(x0[j] * QSCALE);
                qn[kq][4 + j] = (__bf16)(x1[j] * QSCALE);
            }
        }
    }

    f32x16 acc_o0 = {}, acc_o1 = {};       // O [q x d]: dt=0,1
    float lsum = 0.0f;                     // lane-local: q-row l31, own kv residues

    // staging maps (DMA: wave-uniform LDS base + lane*16)
    const int krow = tid >> 3;                          // K row within 32-half
    const int kcg  = (tid & 7) ^ ((tid >> 3) & 7);      // K col-group (swizzled src)
    const int vd0  = tid >> 3;                          // V d within 32-half
    const int vkg  = (tid & 7) ^ ((tid >> 3) & 7);      // V kv-group (swizzled src)

    auto stage = [&](int jt, int b) {
        GLOAD_LDS16(khb + (size_t)(jt * BN + krow) * DH + kcg * 8,
                    (char*)Ks[b] + tid * 16);
        GLOAD_LDS16(khb + (size_t)(jt * BN + 32 + krow) * DH + kcg * 8,
                    (char*)Ks[b] + 4096 + tid * 16);
        GLOAD_LDS16(vhb + (size_t)vd0 * SEQ + jt * BN + vkg * 8,
                    (char*)Vs[b] + tid * 16);
        GLOAD_LDS16(vhb + (size_t)(32 + vd0) * SEQ + jt * BN + vkg * 8,
                    (char*)Vs[b] + 4096 + tid * 16);
    };

    // ---- prologue: tile jt0 -> buf0 ----
    stage(jt0, 0);
    __syncthreads();                       // drains vmcnt(0), buf0 ready

    int buf = 0;
    for (int jt = jt0; jt < jt_end; ++jt) {
        if (jt + 1 < jt_end) stage(jt + 1, buf ^ 1);   // in flight during compute

        // ---- S^T = K * Q^T (2 kv-tiles x 4 k-steps, 8 MFMA) ----
        const char* Kb = (const char*)Ks[buf];
        const char* Vb = (const char*)Vs[buf];
        f32x16 sa0 = {}, sa1 = {};
        __builtin_amdgcn_s_setprio(1);
        #pragma unroll
        for (int kq = 0; kq < 4; ++kq) {
            bf16x8 kf0 = *(const bf16x8*)(Kb + l31 * 128 +
                                          (((2 * kq + hb) ^ (lane & 7)) << 4));
            bf16x8 kf1 = *(const bf16x8*)(Kb + (32 + l31) * 128 +
                                          (((2 * kq + hb) ^ (lane & 7)) << 4));
            sa0 = __builtin_amdgcn_mfma_f32_32x32x16_bf16(kf0, qn[kq], sa0, 0, 0, 0);
            sa1 = __builtin_amdgcn_mfma_f32_32x32x16_bf16(kf1, qn[kq], sa1, 0, 0, 0);
        }
        __builtin_amdgcn_s_setprio(0);

        if (jt >= 2 * mt2) {               // diagonal region: causal mask
            #pragma unroll
            for (int reg = 0; reg < 16; ++reg) {
                const int kvr = jt * 64 + (reg & 3) + 8 * (reg >> 2) + 4 * hb;
                if (kvr > qg)      sa0[reg] = -1e30f;
                if (kvr + 32 > qg) sa1[reg] = -1e30f;
            }
        }

        // ---- softmax: in-place exp2, lane-local l sum, pack to u32 quads ----
        u32 pk[8][2];                      // all static-indexed (rule #20)
        #pragma unroll
        for (int sp = 0; sp < 4; ++sp) {
            float e0 = EXP2F(sa0[4 * sp + 0]), e1 = EXP2F(sa0[4 * sp + 1]);
            float e2 = EXP2F(sa0[4 * sp + 2]), e3 = EXP2F(sa0[4 * sp + 3]);
            float f0 = EXP2F(sa1[4 * sp + 0]), f1 = EXP2F(sa1[4 * sp + 1]);
            float f2 = EXP2F(sa1[4 * sp + 2]), f3 = EXP2F(sa1[4 * sp + 3]);
            lsum += ((e0 + e1) + (e2 + e3)) + ((f0 + f1) + (f2 + f3));
            pk[sp][0]     = pk2(e0, e1); pk[sp][1]     = pk2(e2, e3);
            pk[4 + sp][0] = pk2(f0, f1); pk[4 + sp][1] = pk2(f2, f3);
        }

        // ---- O += P V. A-frag = own quads directly (kv-permuted V slots) ----
        __builtin_amdgcn_s_setprio(1);
        #pragma unroll
        for (int s = 0; s < 4; ++s) {
            u32x4 uv;
            uv[0] = pk[2 * s][0];
            uv[1] = pk[2 * s][1];
            uv[2] = pk[2 * s + 1][0];
            uv[3] = pk[2 * s + 1][1];
            bf16x8 pf = __builtin_bit_cast(bf16x8, uv);
            bf16x8 vf0 = *(const bf16x8*)(Vb + l31 * 128 +
                                          (((2 * s + hb) ^ (lane & 7)) << 4));
            bf16x8 vf1 = *(const bf16x8*)(Vb + (32 + l31) * 128 +
                                          (((2 * s + hb) ^ (lane & 7)) << 4));
            acc_o0 = __builtin_amdgcn_mfma_f32_32x32x16_bf16(pf, vf0, acc_o0, 0, 0, 0);
            acc_o1 = __builtin_amdgcn_mfma_f32_32x32x16_bf16(pf, vf1, acc_o1, 0, 0, 0);
        }
        __builtin_amdgcn_s_setprio(0);

        if (jt + 1 < jt_end) __syncthreads();  // drains gl_lds; readers of buf done
        buf ^= 1;
    }

    // full l for q-row l31: both kv-parity halves
    const float ltot = lsum + __shfl_xor(lsum, 32, 64);

    if (2 * mt2 + 2 <= 8) {
        // ---- single-chunk q-tile: broadcast l per C-row, write out direct
        float* oh = out + (size_t)bh * SEQ * DH;
        #pragma unroll
        for (int reg = 0; reg < 16; ++reg) {
            const int rr = (reg & 3) + 8 * (reg >> 2) + 4 * hb;
            const float lr = __shfl(ltot, rr, 64);   // lane rr holds l(q=w*32+rr)
            const float inv = 1.0f / lr;
            const int row = q0 + w * 32 + rr;
            oh[(size_t)row * DH + l31]      = acc_o0[reg] * inv;
            oh[(size_t)row * DH + 32 + l31] = acc_o1[reg] * inv;
        }
    } else {
        // ---- partials out (O in bf16; l in f32, lane-owned row) ----
        const int slot = (bh * 16 + mt2) * 4 + chunk;
        __bf16* po = opart + (size_t)slot * 8192;
        #pragma unroll
        for (int reg = 0; reg < 16; ++reg) {
            const int row = w * 32 + (reg & 3) + 8 * (reg >> 2) + 4 * hb;
            po[row * 64 + l31]      = (__bf16)acc_o0[reg];
            po[row * 64 + 32 + l31] = (__bf16)acc_o1[reg];
        }
        if (hb == 0) lpart[(size_t)slot * 128 + w * 32 + l31] = ltot;
    }
}

// ---------------- reduce: sum bf16 chunks, normalize (mt2 >= 4 only) ----------------
__global__ __launch_bounds__(256)
void fa_reduce(const __bf16* __restrict__ opart, const float* __restrict__ lpart,
               float* __restrict__ out)
{
    const int bx = blockIdx.x;             // 288 = 8 XCDs x 3 headgrp x 12
    const int xcd = bx & 7;
    const int r2 = bx >> 3;                // 0..35
    const int bh = (r2 / 12) * 8 + xcd;    // co-locate with producer XCD
    const int mt2 = 4 + (r2 % 12);
    const int nc = (mt2 >> 2) + 1;         // ceil((2*mt2+2)/8)
    const int base = (bh * 16 + mt2) * 4;
    const int tid = threadIdx.x;
    #pragma unroll
    for (int rnd = 0; rnd < 8; ++rnd) {
        const int flat = rnd * 1024 + tid * 4;
        const int row = flat >> 6;
        float o0 = 0, o1 = 0, o2 = 0, o3 = 0, l = 0;
        for (int c = 0; c < nc; ++c) {
            bf16x4 ov = *(const bf16x4*)(opart + (size_t)(base + c) * 8192 + flat);
            o0 += (float)ov[0]; o1 += (float)ov[1]; o2 += (float)ov[2]; o3 += (float)ov[3];
            l += lpart[(size_t)(base + c) * 128 + row];
        }
        const float inv = 1.0f / l;
        f32x4 res = { o0 * inv, o1 * inv, o2 * inv, o3 * inv };
        *(f32x4*)(out + (size_t)bh * SEQ * DH + (size_t)mt2 * 8192 + flat) = res;
    }
}

// ---------------- fallback: R1 self-contained kernel ----------------
__global__ __launch_bounds__(256, 2)
void fa_causal_kernel(const float* __restrict__ q, const float* __restrict__ k,
                      const float* __restrict__ v, float* __restrict__ out)
{
    const int mt = 31 - (blockIdx.x & 31);
    const int bh = blockIdx.x >> 5;
    const int tid = threadIdx.x;
    const int w = tid >> 6, lane = tid & 63;
    const int g = lane >> 4, li = lane & 15;
    const int m0 = mt * 64;
    __shared__ __bf16 KsF[BN][LDK];
    __shared__ __bf16 VsF[DH][LDK];
    __shared__ __bf16 PsF[4][16][LDK];
    const size_t head_off = (size_t)bh * SEQ * DH;
    const float* qh = q + head_off;
    const float* kh = k + head_off;
    const float* vh = v + head_off;
    float* oh = out + head_off;
    const int qrow = m0 + w * 16 + li;
    bf16x8 qf[2];
    {
        const float* qp = qh + (size_t)qrow * DH + g * 8;
        #pragma unroll
        for (int c = 0; c < 2; ++c) {
            const float* p = qp + c * 32;
            #pragma unroll
            for (int jj = 0; jj < 8; ++jj) qf[c][jj] = (__bf16)p[jj];
        }
    }
    f32x4 acc[4] = {};
    float mrow[4], lrow[4];
    #pragma unroll
    for (int r = 0; r < 4; ++r) { mrow[r] = -1e30f; lrow[r] = 0.0f; }
    const float scale = 0.125f;
    const int srow = tid >> 2, scol = (tid & 3) * 16;
    for (int jt = 0; jt <= mt; ++jt) {
        const int kv0 = jt * BN;
        __syncthreads();
        {
            const float* kp = kh + (size_t)(kv0 + srow) * DH + scol;
            __bf16 tmp[16];
            #pragma unroll
            for (int jj = 0; jj < 16; ++jj) tmp[jj] = (__bf16)kp[jj];
            *(bf16x8*)&KsF[srow][scol]     = *(bf16x8*)&tmp[0];
            *(bf16x8*)&KsF[srow][scol + 8] = *(bf16x8*)&tmp[8];
            const float* vp = vh + (size_t)(kv0 + srow) * DH + scol;
            #pragma unroll
            for (int jj = 0; jj < 16; ++jj) VsF[scol + jj][srow] = (__bf16)vp[jj];
        }
        __syncthreads();
        float s4[4][4];
        #pragma unroll
        for (int t = 0; t < 4; ++t) {
            f32x4 sa = {};
            #pragma unroll
            for (int c = 0; c < 2; ++c) {
                bf16x8 kfr = *(const bf16x8*)&KsF[t * 16 + li][c * 32 + g * 8];
                sa = __builtin_amdgcn_mfma_f32_16x16x32_bf16(qf[c], kfr, sa, 0, 0, 0);
            }
            #pragma unroll
            for (int r = 0; r < 4; ++r) s4[t][r] = sa[r] * scale;
        }
        if (jt == mt) {
            #pragma unroll
            for (int t = 0; t < 4; ++t) {
                const int col = kv0 + t * 16 + li;
                #pragma unroll
                for (int r = 0; r < 4; ++r)
                    if (col > m0 + w * 16 + g * 4 + r) s4[t][r] = -1e30f;
            }
        }
        #pragma unroll
        for (int r = 0; r < 4; ++r) {
            float mx = fmaxf(fmaxf(s4[0][r], s4[1][r]), fmaxf(s4[2][r], s4[3][r]));
            #pragma unroll
            for (int off = 1; off < 16; off <<= 1)
                mx = fmaxf(mx, __shfl_xor(mx, off, 64));
            const float mnew = fmaxf(mrow[r], mx);
            const float alpha = __expf(mrow[r] - mnew);
            mrow[r] = mnew;
            float ps = 0.0f;
            #pragma unroll
            for (int t = 0; t < 4; ++t) {
                const float p = __expf(s4[t][r] - mnew);
                s4[t][r] = p;
                ps += p;
            }
            #pragma unroll
            for (int off = 1; off < 16; off <<= 1)
                ps += __shfl_xor(ps, off, 64);
            lrow[r] = lrow[r] * alpha + ps;
            #pragma unroll
            for (int t = 0; t < 4; ++t) acc[t][r] *= alpha;
        }
        #pragma unroll
        for (int t = 0; t < 4; ++t)
            #pragma unroll
            for (int r = 0; r < 4; ++r)
                PsF[w][g * 4 + r][t * 16 + li] = (__bf16)s4[t][r];
        __syncthreads();
        #pragma unroll
        for (int c = 0; c < 2; ++c) {
            bf16x8 pf = *(const bf16x8*)&PsF[w][li][c * 32 + g * 8];
            #pragma unroll
            for (int t = 0; t < 4; ++t) {
                bf16x8 vfr = *(const bf16x8*)&VsF[t * 16 + li][c * 32 + g * 8];
                acc[t] = __builtin_amdgcn_mfma_f32_16x16x32_bf16(pf, vfr, acc[t], 0, 0, 0);
            }
        }
    }
    #pragma unroll
    for (int r = 0; r < 4; ++r) {
        const int row = m0 + w * 16 + g * 4 + r;
        const float inv = 1.0f / lrow[r];
        float* op = oh + (size_t)row * DH + li;
        #pragma unroll
        for (int t = 0; t < 4; ++t) op[t * 16] = acc[t][r] * inv;
    }
}

extern "C" void kernel_launch(void* const* d_in, const int* in_sizes, int n_in,
                              void* d_out, int out_size, void* d_ws, size_t ws_size,
                              hipStream_t stream) {
    (void)in_sizes; (void)n_in; (void)out_size;
    const float* q = (const float*)d_in[0];
    const float* k = (const float*)d_in[1];
    const float* v = (const float*)d_in[2];
    float* out = (float*)d_out;

    if (ws_size >= WS_FA11) {
        __bf16* ks = (__bf16*)d_ws;
        __bf16* vt = ks + ELEMS_PER_TENSOR;
        __bf16* opart = (__bf16*)((char*)d_ws + WS_KV);
        float* lpart = (float*)((char*)d_ws + WS_KV + (size_t)NSLOT * 8192 * 2);
        prep_kernel<<<dim3(1536 + 768), dim3(256), 0, stream>>>(k, v, ks, vt);
        fa24_kernel<<<dim3(960), dim3(256), 0, stream>>>(q, ks, vt, opart, lpart, out);
        fa_reduce<<<dim3(288), dim3(256), 0, stream>>>(opart, lpart, out);
    } else {
        fa_causal_kernel<<<dim3(NHEADS * 32), dim3(256), 0, stream>>>(q, k, v, out);
    }
}